// Round 18
// baseline (428.049 us; speedup 1.0000x reference)
//
#include <hip/hip_runtime.h>

#define BT    4      // batch tile per block (2 blocks/CU)
#define HID   64
#define SEQ   512
#define NOUT  12
#define XST   514    // x row stride: 512 data + 1 dup col + pad

typedef float  f32x4 __attribute__((ext_vector_type(4)));
typedef _Float16 f16x8 __attribute__((ext_vector_type(8)));
typedef unsigned int   u32;
typedef unsigned short u16;

union FW { f16x8 v; u32 w[4]; uint4 q; };

__device__ __forceinline__ float rcpf(float x) { return __builtin_amdgcn_rcpf(x); }
__device__ __forceinline__ float e2(float x)   { return __builtin_amdgcn_exp2f(x); }
__device__ __forceinline__ u16 f16b(float a) {
    union { _Float16 f; u16 u; } p; p.f = (_Float16)a; return p.u;
}
// Load 8 consecutive f32 weights, scale, convert to one f16x8 fragment.
__device__ __forceinline__ f16x8 f16row(const float* src, float scale) {
    float f[8];
    *(float4*)&f[0] = *(const float4*)src;
    *(float4*)&f[4] = *(const float4*)(src + 4);
    union { f16x8 v; _Float16 h[8]; } H;
#pragma unroll
    for (int i = 0; i < 8; ++i) H.h[i] = (_Float16)(f[i] * scale);
    return H.v;
}

#define MFMA(A, B, C) __builtin_amdgcn_mfma_f32_16x16x32_f16((A), (B), (C), 0, 0, 0)

// h-fragment chunk for MFMA-lane L at position swz(L) = L ^ (L>>3).
__device__ __forceinline__ int swz(int c) { return c ^ (c >> 3); }
// DPP ctl must be a compile-time constant -> template parameter.
template <int CTL>
__device__ __forceinline__ float dppf(float v) {
    return __int_as_float(__builtin_amdgcn_mov_dpp(__float_as_int(v), CTL, 0xF, 0xF, true));
}

// 2-blocks/CU variant: BT=4, 512 threads (8 waves), grid 512 -> two
// independently-barriered blocks per CU slide phases (MFMA of one block
// overlaps trans/ew of the other). Wave owns 2 row-tiles (units 8w..8w+7);
// weights pure f16 (log2e-scaled) to fit 128 VGPR at 4 waves/EU.
// ew identity per lane: ly=n>>3, bb=n&3, uo=8w+4*((n>>2)&1)+qg, reached via
// row_shr:{4,8,12} DPP selects. One barrier/step; r16 exp2/unroll kept.
__global__ void __launch_bounds__(512, 4)
lstm2_fused(
    const float* __restrict__ x,      // [B, SEQ, 1]
    const float* __restrict__ w_ih0,  // [256, 1]
    const float* __restrict__ w_hh0,  // [256, 64]
    const float* __restrict__ b_ih0,  // [256]
    const float* __restrict__ b_hh0,  // [256]
    const float* __restrict__ w_ih1,  // [256, 64]
    const float* __restrict__ w_hh1,  // [256, 64]
    const float* __restrict__ b_ih1,  // [256]
    const float* __restrict__ b_hh1,  // [256]
    const float* __restrict__ fc_w,   // [12, 64]
    const float* __restrict__ fc_b,   // [12]
    float* __restrict__ out)          // [B, 12]
{
    __shared__ float xs[BT][XST];          // 8.2 KB
    __shared__ u32   hf[2048];             // 8 KB [dbuf][layer][kt][chunk]
    __shared__ float h1last[BT][HID + 4];  // 1.1 KB

    const int tid  = threadIdx.x;
    const int w    = tid >> 6;        // wave: units 8w..8w+7 (2 tiles)
    const int lane = tid & 63;
    const int n    = lane & 15;       // B-col / tile-row lane index
    const int qg   = lane >> 4;       // k-group & unit-in-tile (0..3)
    const int b0   = blockIdx.x * BT;

    const float L2E  = 1.44269504088896340736f;
    const float TL2E = 2.f * L2E;

    // ---- A fragments (pure f16, gate-interleaved, log2e-scaled): 12 frags ----
    const int gA    = n & 3;                              // gate of this A row
    const int arowA = gA * 64 + 8 * w + (n >> 2);         // tile A gate-row
    const int arowB = arowA + 4;                          // tile B gate-row
    const float asc = (gA == 2) ? TL2E : L2E;
    f16x8 A0[2][2], AI[2][2], AH[2][2];                   // [tile][kt]
#pragma unroll
    for (int kt = 0; kt < 2; ++kt) {
        A0[0][kt] = f16row(&w_hh0[arowA * HID + 32*kt + 8*qg], asc);
        A0[1][kt] = f16row(&w_hh0[arowB * HID + 32*kt + 8*qg], asc);
        AI[0][kt] = f16row(&w_ih1[arowA * HID + 32*kt + 8*qg], asc);
        AI[1][kt] = f16row(&w_ih1[arowB * HID + 32*kt + 8*qg], asc);
        AH[0][kt] = f16row(&w_hh1[arowA * HID + 32*kt + 8*qg], asc);
        AH[1][kt] = f16row(&w_hh1[arowB * HID + 32*kt + 8*qg], asc);
    }

    // ---- MFMA C-in biases (exp2 domain), per tile-layer (D-row identity) ----
    const int ua = 8 * w + qg, ub = ua + 4;
    f32x4 bA0, bB0, bA1, bB1;
#pragma unroll
    for (int r = 0; r < 4; ++r) {
        const float sc = (r == 2) ? TL2E : L2E;
        bA0[r] = (b_ih0[64*r + ua] + b_hh0[64*r + ua]) * sc;
        bB0[r] = (b_ih0[64*r + ub] + b_hh0[64*r + ub]) * sc;
        bA1[r] = (b_ih1[64*r + ua] + b_hh1[64*r + ua]) * sc;
        bB1[r] = (b_ih1[64*r + ub] + b_hh1[64*r + ub]) * sc;
    }

    // ---- ew identity: ly = n>>3, bb = n&3, uo = 8w + 4*((n>>2)&1) + qg ----
    const int  ly = n >> 3;
    const int  bb = n & 3;
    const int  uo = 8 * w + 4 * ((n >> 2) & 1) + qg;
    const bool m1 = (n >> 2) & 1;     // tile-B identity
    float wihL[4], bie0[4];
#pragma unroll
    for (int r = 0; r < 4; ++r) {
        const float sc = (r == 2) ? TL2E : L2E;
        wihL[r] = (ly == 0) ? w_ih0[64*r + uo] * sc : 0.f;
        bie0[r] = m1 ? bB0[r] : bA0[r];   // layer-0 bias of my identity (prologue)
    }

    // ---- addressing (loop-invariant) ----
    const int rb   = swz(lane) << 2;                    // frag read: dword base
    const int wb16 = (ly << 10) + ((uo >> 5) << 9)
                   + (swz(((uo & 31) >> 3) * 16 + bb) << 3) + (uo & 7);
    const char* hfB = (const char*)hf + rb * 4;         // read base (bytes)
    u16*        hwB = (u16*)hf + wb16;                  // write base

    // ---- stage x (+dup col 512); zero frag buffer ----
    for (int i = tid; i < BT * SEQ; i += 512) {
        int b = i >> 9, t = i & (SEQ - 1);
        xs[b][t] = x[(size_t)(b0 + b) * SEQ + t];
    }
    if (tid < BT) xs[tid][SEQ] = x[(size_t)(b0 + tid) * SEQ + (SEQ - 1)];
    for (int i = tid; i < 2048; i += 512) hf[i] = 0u;
    float c = 0.f, h = 0.f;
    __syncthreads();

    // ===== prologue: h0(0) from x(0) only; h1(-1)=0 stays zeroed =====
    if (ly == 0) {
        float xv = xs[bb][0];
        float ig = rcpf(1.f + e2(-fmaf(xv, wihL[0], bie0[0])));
        float gg = fmaf(-2.f, rcpf(1.f + e2(fmaf(xv, wihL[2], bie0[2]))), 1.f);
        float og = rcpf(1.f + e2(-fmaf(xv, wihL[3], bie0[3])));
        c = ig * gg;
        h = og * fmaf(-2.f, rcpf(1.f + e2(c * TL2E)), 1.f);
        hwB[0] = f16b(h);                // dbuf 0
    }
    __syncthreads();

#define STEP(CUR, NXT)                                                         \
    {                                                                          \
        const float xv = *xp2++;                                               \
        FW B00, B01, B10, B11;                                                 \
        B00.q = *(const uint4*)(hfB + (CUR)*4096 + 0);                         \
        B01.q = *(const uint4*)(hfB + (CUR)*4096 + 1024);                      \
        B10.q = *(const uint4*)(hfB + (CUR)*4096 + 2048);                      \
        B11.q = *(const uint4*)(hfB + (CUR)*4096 + 3072);                      \
        f32x4 a0A = MFMA(A0[0][0], B00.v, bA0);                                \
        f32x4 a0B = MFMA(A0[1][0], B00.v, bB0);                                \
        f32x4 a1A = MFMA(AI[0][0], B00.v, bA1);                                \
        f32x4 a1B = MFMA(AI[1][0], B00.v, bB1);                                \
        a0A = MFMA(A0[0][1], B01.v, a0A);                                      \
        a0B = MFMA(A0[1][1], B01.v, a0B);                                      \
        a1A = MFMA(AH[0][0], B10.v, a1A);                                      \
        a1B = MFMA(AH[1][0], B10.v, a1B);                                      \
        a1A = MFMA(AI[0][1], B01.v, a1A);                                      \
        a1B = MFMA(AI[1][1], B01.v, a1B);                                      \
        a1A = MFMA(AH[0][1], B11.v, a1A);                                      \
        a1B = MFMA(AH[1][1], B11.v, a1B);                                      \
        f32x4 accS;                                                            \
        _Pragma("unroll")                                                      \
        for (int i = 0; i < 4; ++i) {                                          \
            float s4  = dppf<0x114>(a0B[i]);   /* row_shr:4  */                \
            float s8  = dppf<0x118>(a1A[i]);   /* row_shr:8  */                \
            float s12 = dppf<0x11C>(a1B[i]);   /* row_shr:12 */                \
            float v0 = m1 ? s4  : a0A[i];                                      \
            float v1 = m1 ? s12 : s8;                                          \
            accS[i] = ly ? v1 : v0;                                            \
        }                                                                      \
        float ig = rcpf(1.f + e2(-fmaf(xv, wihL[0], accS[0])));                \
        float fg = rcpf(1.f + e2(-fmaf(xv, wihL[1], accS[1])));                \
        float gg = fmaf(-2.f, rcpf(1.f + e2(fmaf(xv, wihL[2], accS[2]))), 1.f);\
        float og = rcpf(1.f + e2(-fmaf(xv, wihL[3], accS[3])));                \
        c = fg * c + ig * gg;                                                  \
        h = og * fmaf(-2.f, rcpf(1.f + e2(c * TL2E)), 1.f);                    \
        hwB[(NXT) * 2048] = f16b(h);                                           \
        __syncthreads();                                                       \
    }

    {
        const float* xp2 = &xs[bb][1];   // x(t+1) for t = 0
        for (int t2 = 0; t2 < SEQ; t2 += 2) {
            STEP(0, 1);
            STEP(1, 0);
        }
    }
#undef STEP

    // layer-1 lanes hold h1(511)
    if (ly) h1last[bb][uo] = h;
    __syncthreads();

    // ===== final projection: out[b][o] = fc_b[o] + h1(511) . fc_w[o] =====
    if (tid < BT * NOUT) {
        int b = tid / NOUT, o = tid % NOUT;
        float acc = fc_b[o];
#pragma unroll
        for (int j = 0; j < HID; ++j)
            acc = fmaf(fc_w[o * HID + j], h1last[b][j], acc);
        out[(size_t)(b0 + b) * NOUT + o] = acc;
    }
}

extern "C" void kernel_launch(void* const* d_in, const int* in_sizes, int n_in,
                              void* d_out, int out_size, void* d_ws, size_t ws_size,
                              hipStream_t stream) {
    const float* x     = (const float*)d_in[0];
    const float* w_ih0 = (const float*)d_in[1];
    const float* w_hh0 = (const float*)d_in[2];
    const float* b_ih0 = (const float*)d_in[3];
    const float* b_hh0 = (const float*)d_in[4];
    const float* w_ih1 = (const float*)d_in[5];
    const float* w_hh1 = (const float*)d_in[6];
    const float* b_ih1 = (const float*)d_in[7];
    const float* b_hh1 = (const float*)d_in[8];
    const float* fc_w  = (const float*)d_in[9];
    const float* fc_b  = (const float*)d_in[10];

    const int B = in_sizes[0] / SEQ;          // 2048
    dim3 grid(B / BT);                        // 512 blocks -> 2 blocks/CU
    lstm2_fused<<<grid, 512, 0, stream>>>(x, w_ih0, w_hh0, b_ih0, b_hh0,
                                          w_ih1, w_hh1, b_ih1, b_hh1,
                                          fc_w, fc_b, (float*)d_out);
}

// Round 19
// 332.123 us; speedup vs baseline: 1.2888x; 1.2888x over previous
//
#include <hip/hip_runtime.h>

#define BT    8      // batch tile per block
#define HID   64
#define SEQ   512
#define NOUT  12
#define XST   514    // x row stride: 512 data + 1 dup col + pad

typedef float  f32x4 __attribute__((ext_vector_type(4)));
typedef _Float16 f16x8 __attribute__((ext_vector_type(8)));
typedef unsigned int   u32;
typedef unsigned short u16;

union FW { f16x8 v; u32 w[4]; uint4 q; };

__device__ __forceinline__ float rcpf(float x) { return __builtin_amdgcn_rcpf(x); }
__device__ __forceinline__ float e2(float x)   { return __builtin_amdgcn_exp2f(x); }
__device__ __forceinline__ u16 f16b(float a) {
    union { _Float16 f; u16 u; } p; p.f = (_Float16)a; return p.u;
}
// Load 8 consecutive f32 weights, scale, convert to one f16x8 fragment.
// (r18 measured: dropping the f16-lo correction leaves absmax unchanged.)
__device__ __forceinline__ f16x8 f16row(const float* src, float scale) {
    float f[8];
    *(float4*)&f[0] = *(const float4*)src;
    *(float4*)&f[4] = *(const float4*)(src + 4);
    union { f16x8 v; _Float16 h[8]; } H;
#pragma unroll
    for (int i = 0; i < 8; ++i) H.h[i] = (_Float16)(f[i] * scale);
    return H.v;
}

#define MFMA(A, B, C) __builtin_amdgcn_mfma_f32_16x16x32_f16((A), (B), (C), 0, 0, 0)

// h-fragment chunk for MFMA-lane L at position swz(L) = L ^ (L>>3).
__device__ __forceinline__ int swz(int c) { return c ^ (c >> 3); }

// r16 champion structure (16 waves, gate-interleaved rows, layer-split ew via
// row_shr:8, bias in MFMA C-in, exp2-domain weights, unroll x2, one barrier
// per step). Round-19 edit: W-lo correction deleted (r18 proved absmax is
// identical without it) -> 6 MFMA/step, no merge FMAs, ~32 fewer registers.
__global__ void __launch_bounds__(1024)
lstm2_fused(
    const float* __restrict__ x,      // [B, SEQ, 1]
    const float* __restrict__ w_ih0,  // [256, 1]
    const float* __restrict__ w_hh0,  // [256, 64]
    const float* __restrict__ b_ih0,  // [256]
    const float* __restrict__ b_hh0,  // [256]
    const float* __restrict__ w_ih1,  // [256, 64]
    const float* __restrict__ w_hh1,  // [256, 64]
    const float* __restrict__ b_ih1,  // [256]
    const float* __restrict__ b_hh1,  // [256]
    const float* __restrict__ fc_w,   // [12, 64]
    const float* __restrict__ fc_b,   // [12]
    float* __restrict__ out)          // [B, 12]
{
    __shared__ float xs[BT][XST];          // 16.4 KB
    __shared__ u32   hf[2048];             // 8 KB [dbuf][layer][kt][chunk]
    __shared__ float h1last[BT][HID + 4];  // 2.1 KB

    const int tid  = threadIdx.x;
    const int wid  = tid >> 6;        // wave = unit band (units 4*wid..4*wid+3)
    const int lane = tid & 63;
    const int n    = lane & 15;       // B-col (batch) / tile-row lane index
    const int qg   = lane >> 4;       // k-group & owned-unit selector (0..3)
    const int b0   = blockIdx.x * BT;

    const float L2E  = 1.44269504088896340736f;
    const float TL2E = 2.f * L2E;

    // ---- A fragments, gate-interleaved rows, log2e-scaled: 6 x f16x8 ----
    const int ag   = n & 3;                               // gate of this A row
    const int arow = ag * 64 + 4 * wid + (n >> 2);        // original gate row
    const float asc = (ag == 2) ? TL2E : L2E;             // row scale
    f16x8 A0[2], AI[2], AH[2];
#pragma unroll
    for (int kt = 0; kt < 2; ++kt) {
        A0[kt] = f16row(&w_hh0[arow * HID + 32*kt + 8*qg], asc);
        AI[kt] = f16row(&w_ih1[arow * HID + 32*kt + 8*qg], asc);
        AH[kt] = f16row(&w_hh1[arow * HID + 32*kt + 8*qg], asc);
    }

    // ---- ew identity: (layer ly, batch bb, unit uo) ----
    const int ly = (n >> 3) & 1;
    const int bb = n & 7;
    const int uo = 4 * wid + qg;

    // MFMA C-in biases + wih, scaled to the exp2 domain (gate r scale sc[r])
    f32x4 bias0q, bias1q;
    float wihL[4];
#pragma unroll
    for (int r = 0; r < 4; ++r) {
        const int row = 64 * r + uo;
        const float sc = (r == 2) ? TL2E : L2E;
        bias0q[r] = (b_ih0[row] + b_hh0[row]) * sc;
        bias1q[r] = (b_ih1[row] + b_hh1[row]) * sc;
        wihL[r]   = (ly == 0) ? w_ih0[row] * sc : 0.f;
    }

    // ---- addressing (loop-invariant) ----
    const int rb   = swz(lane) << 2;                    // frag read: dword base
    const int ktw  = uo >> 5;                           // h write: kt block
    const int qgc  = (uo & 31) >> 3;                    // consumer k-group
    const int wb16 = (ly << 10) + (ktw << 9) + (swz(qgc * 16 + bb) << 3) + (uo & 7);
    const char* hfB = (const char*)hf + rb * 4;         // read base (bytes)
    u16*        hwB = (u16*)hf + wb16;                  // write base

    // ---- stage x (+dup col 512); zero frag buffers ----
    for (int i = tid; i < BT * SEQ; i += 1024) {
        int b = i >> 9, t = i & (SEQ - 1);
        xs[b][t] = x[(size_t)(b0 + b) * SEQ + t];
    }
    if (tid < BT) xs[tid][SEQ] = x[(size_t)(b0 + tid) * SEQ + (SEQ - 1)];
    for (int i = tid; i < 2048; i += 1024) hf[i] = 0u;
    float c = 0.f, h = 0.f;
    __syncthreads();

    // ===== prologue: h0(0) from x(0) only; h1(-1)=0 stays zeroed =====
    if (ly == 0) {
        float xv = xs[bb][0];
        float ig = rcpf(1.f + e2(-fmaf(xv, wihL[0], bias0q[0])));
        float gg = fmaf(-2.f, rcpf(1.f + e2(fmaf(xv, wihL[2], bias0q[2]))), 1.f);
        float og = rcpf(1.f + e2(-fmaf(xv, wihL[3], bias0q[3])));
        c = ig * gg;
        h = og * fmaf(-2.f, rcpf(1.f + e2(c * TL2E)), 1.f);
        hwB[0] = f16b(h);                // dbuf 0
    }
    __syncthreads();

#define STEP(CUR, NXT)                                                         \
    {                                                                          \
        const float xv = *xp2++;                                               \
        FW B00, B01, B10, B11;                                                 \
        B00.q = *(const uint4*)(hfB + (CUR)*4096 + 0);                         \
        B01.q = *(const uint4*)(hfB + (CUR)*4096 + 1024);                      \
        B10.q = *(const uint4*)(hfB + (CUR)*4096 + 2048);                      \
        B11.q = *(const uint4*)(hfB + (CUR)*4096 + 3072);                      \
        f32x4 acc0 = MFMA(A0[0], B00.v, bias0q);                               \
        f32x4 acc1 = MFMA(AI[0], B00.v, bias1q);                               \
        acc0 = MFMA(A0[1], B01.v, acc0);                                       \
        acc1 = MFMA(AH[0], B10.v, acc1);                                       \
        acc1 = MFMA(AI[1], B01.v, acc1);                                       \
        acc1 = MFMA(AH[1], B11.v, acc1);                                       \
        f32x4 accS;                                                            \
        _Pragma("unroll")                                                      \
        for (int i = 0; i < 4; ++i) {                                          \
            float s = __int_as_float(__builtin_amdgcn_mov_dpp(                 \
                          __float_as_int(acc1[i]), 0x118, 0xF, 0xF, true));    \
            accS[i] = ly ? s : acc0[i];                                        \
        }                                                                      \
        float ig = rcpf(1.f + e2(-fmaf(xv, wihL[0], accS[0])));                \
        float fg = rcpf(1.f + e2(-fmaf(xv, wihL[1], accS[1])));                \
        float gg = fmaf(-2.f, rcpf(1.f + e2(fmaf(xv, wihL[2], accS[2]))), 1.f);\
        float og = rcpf(1.f + e2(-fmaf(xv, wihL[3], accS[3])));                \
        c = fg * c + ig * gg;                                                  \
        h = og * fmaf(-2.f, rcpf(1.f + e2(c * TL2E)), 1.f);                    \
        hwB[(NXT) * 2048] = f16b(h);                                           \
        __syncthreads();                                                       \
    }

    {
        const float* xp2 = &xs[bb][1];   // x(t+1) for t = 0
        for (int t2 = 0; t2 < SEQ; t2 += 2) {
            STEP(0, 1);
            STEP(1, 0);
        }
    }
#undef STEP

    // layer-1 lanes hold h1(511)
    if (ly) h1last[bb][uo] = h;
    __syncthreads();

    // ===== final projection: out[b][o] = fc_b[o] + h1(511) . fc_w[o] =====
    if (tid < BT * NOUT) {
        int b = tid / NOUT, o = tid % NOUT;
        float acc = fc_b[o];
#pragma unroll
        for (int j = 0; j < HID; ++j)
            acc = fmaf(fc_w[o * HID + j], h1last[b][j], acc);
        out[(size_t)(b0 + b) * NOUT + o] = acc;
    }
}

extern "C" void kernel_launch(void* const* d_in, const int* in_sizes, int n_in,
                              void* d_out, int out_size, void* d_ws, size_t ws_size,
                              hipStream_t stream) {
    const float* x     = (const float*)d_in[0];
    const float* w_ih0 = (const float*)d_in[1];
    const float* w_hh0 = (const float*)d_in[2];
    const float* b_ih0 = (const float*)d_in[3];
    const float* b_hh0 = (const float*)d_in[4];
    const float* w_ih1 = (const float*)d_in[5];
    const float* w_hh1 = (const float*)d_in[6];
    const float* b_ih1 = (const float*)d_in[7];
    const float* b_hh1 = (const float*)d_in[8];
    const float* fc_w  = (const float*)d_in[9];
    const float* fc_b  = (const float*)d_in[10];

    const int B = in_sizes[0] / SEQ;          // 2048
    dim3 grid(B / BT);                        // 256 blocks -> 1 block/CU, 16 waves
    lstm2_fused<<<grid, 1024, 0, stream>>>(x, w_ih0, w_hh0, b_ih0, b_hh0,
                                           w_ih1, w_hh1, b_ih1, b_hh1,
                                           fc_w, fc_b, (float*)d_out);
}